// Round 8
// baseline (322.612 us; speedup 1.0000x reference)
//
#include <hip/hip_runtime.h>
#include <math.h>

#define N 128
#define B 8
#define CI 32
#define CO 32
#define M1 4
#define M2 5
#define IK (CI*CO)       // 1024
#define IKP (IK*M1)      // 4096
#define IKQ (IK*M2)      // 5120
#define TWO_PI_F 6.2831853071795864769f

// 4 v_fma per cmadd, guaranteed
__device__ __forceinline__ float2 cmul(float2 a, float2 b){
    return make_float2(fmaf(a.x,b.x,-(a.y*b.y)), fmaf(a.x,b.y,a.y*b.x));
}
__device__ __forceinline__ float2 cmadd(float2 acc, float2 a, float2 b){
    acc.x = fmaf(a.x, b.x, fmaf(-a.y, b.y, acc.x));
    acc.y = fmaf(a.x, b.y, fmaf( a.y, b.x, acc.y));
    return acc;
}

// A1T[o][ik*M1+p] = 1/(i*2pi*f(o) - wp1[ik,p]); freq-major for contiguous per-o slices
__global__ void k_A1T(const float* wr_, const float* wi_, const float* t_, float2* A1T){
    int idx = blockIdx.x*256 + threadIdx.x;      // [0, N*IKP)
    int o   = idx >> 12;                          // /IKP
    int ikp = idx & (IKP-1);
    float d = t_[1]-t_[0];
    float invnd = 1.0f/((float)N*d);
    int kk = (o < N/2) ? o : o - N;
    float lam = TWO_PI_F * (float)kk * invnd;
    float dr = -wr_[ikp];
    float di = lam - wi_[ikp];
    float inv = 1.0f/(dr*dr + di*di);
    A1T[idx] = make_float2(dr*inv, -di*inv);
}

// A2[ikq][x] natural layout
__global__ void k_A2(const float* wr_, const float* wi_, const float* t_, float2* A2){
    int idx = blockIdx.x*256 + threadIdx.x;      // [0, IKQ*N)
    int ikq = idx >> 7; int xx = idx & (N-1);
    float d = t_[1]-t_[0];
    float invnd = 1.0f/((float)N*d);
    int kk = (xx < N/2) ? xx : xx - N;
    float lam = TWO_PI_F * (float)kk * invnd;
    float dr = -wr_[ikq];
    float di = lam - wi_[ikq];
    float inv = 1.0f/(dr*dr + di*di);
    A2[idx] = make_float2(dr*inv, -di*inv);
}

// E[ikp][y] = exp(wp[ikp] * t[y])
__global__ void k_E(const float* wr_, const float* wi_, const float* t_, float2* E){
    int idx = blockIdx.x*256 + threadIdx.x;
    int ikp = idx >> 7; int y = idx & (N-1);
    float t = t_[y];
    float m = expf(wr_[ikp]*t);
    float s, c; sincosf(wi_[ikp]*t, &s, &c);
    E[idx] = make_float2(m*c, m*s);
}

// W2N[ikp][x] = sum_q wr[ik,p,q] * A2[ik,q,x]   (natural layout; coalesced store)
__global__ void k_W2N(const float* wrr, const float* wri, const float2* A2, float2* W2N){
    int idx = blockIdx.x*256 + threadIdx.x;      // [0, IKP*N)
    int ikp = idx >> 7; int xx = idx & (N-1);
    int ik = ikp >> 2; int p = ikp & 3;
    float2 acc = make_float2(0.f,0.f);
    const float* wr0 = wrr + ik*(M1*M2) + p*M2;
    const float* wi0 = wri + ik*(M1*M2) + p*M2;
    const float2* a2 = A2 + (size_t)ik*(M2*N) + xx;
    #pragma unroll
    for(int q=0;q<M2;q++){
        float2 w = make_float2(wr0[q], wi0[q]);
        acc = cmadd(acc, w, a2[q*N]);
    }
    W2N[(size_t)ikp*N + xx] = acc;
}

// ---------- four-step FFT, 128 = 16 x 8 ----------
template<int SIGNPOS, int REALIN, int SCALE>
__global__ void __launch_bounds__(256) k_fft_rows(const void* in_, float2* out){
    const float sgn = SIGNPOS ? 1.0f : -1.0f;
    __shared__ float tre[16*132];
    __shared__ float tim_[16*132];
    __shared__ float zre[16*136];
    __shared__ float zim[16*136];
    int t = threadIdx.x;
    size_t row0 = (size_t)blockIdx.x * 16;

    if(REALIN){
        const float* src = (const float*)in_ + row0*N;
        #pragma unroll
        for(int j=0;j<8;j++){
            int idx = t + 256*j; int r = idx>>7, cl = idx&127;
            tre[r*132+cl] = src[idx];
        }
    } else {
        const float2* src = (const float2*)in_ + row0*N;
        #pragma unroll
        for(int j=0;j<8;j++){
            int idx = t + 256*j; int r = idx>>7, cl = idx&127;
            float2 v = src[idx];
            tre[r*132+cl] = v.x; tim_[r*132+cl] = v.y;
        }
    }
    float t16c[16], t16s[16];
    #pragma unroll
    for(int j=0;j<16;j++){ float s,c; sincosf(sgn*(TWO_PI_F/16.f)*(float)j, &s,&c); t16c[j]=c; t16s[j]=s; }
    __syncthreads();

    int r = t>>4, u = t&15, b = u&7, h = u>>3;
    float xr[16], xi[16];
    #pragma unroll
    for(int a=0;a<16;a++){
        float vr = tre[r*132 + 8*a + b];
        float vi = REALIN ? 0.f : tim_[r*132 + 8*a + b];
        if(h && (a&1)){ vr = -vr; vi = -vi; }
        xr[a]=vr; xi[a]=vi;
    }
    #pragma unroll
    for(int cc=0; cc<8; cc++){
        float yr=0.f, yi=0.f;
        #pragma unroll
        for(int a=0;a<16;a++){
            int j = (a*cc)&15;
            if(REALIN){
                yr = fmaf(xr[a], t16c[j], yr);
                yi = fmaf(xr[a], t16s[j], yi);
            } else {
                yr = fmaf(xr[a], t16c[j], yr); yr = fmaf(-xi[a], t16s[j], yr);
                yi = fmaf(xr[a], t16s[j], yi); yi = fmaf( xi[a], t16c[j], yi);
            }
        }
        int c = 8*h + cc;
        float s,co; sincosf(sgn*(TWO_PI_F/128.f)*(float)(b*c), &s,&co);
        zre[r*136 + b*17 + c] = fmaf(yr,co,-(yi*s));
        zim[r*136 + b*17 + c] = fmaf(yr,s,  yi*co);
    }
    __syncthreads();

    float t8c[8], t8s[8];
    #pragma unroll
    for(int j=0;j<8;j++){ float s,c; sincosf(sgn*(TWO_PI_F/8.f)*(float)j, &s,&c); t8c[j]=c; t8s[j]=s; }
    int r2 = t>>4, c2 = t&15;
    float zr_[8], zi_[8];
    #pragma unroll
    for(int bb=0;bb<8;bb++){ zr_[bb]=zre[r2*136 + bb*17 + c2]; zi_[bb]=zim[r2*136 + bb*17 + c2]; }
    float2* dst = out + (row0 + r2)*N;
    #pragma unroll
    for(int d=0; d<8; d++){
        float Xr=0.f, Xi=0.f;
        #pragma unroll
        for(int bb=0;bb<8;bb++){
            int j=(bb*d)&7;
            Xr = fmaf(zr_[bb], t8c[j], Xr); Xr = fmaf(-zi_[bb], t8s[j], Xr);
            Xi = fmaf(zr_[bb], t8s[j], Xi); Xi = fmaf( zi_[bb], t8c[j], Xi);
        }
        if(SCALE){ Xr *= (1.f/128.f); Xi *= (1.f/128.f); }
        dst[c2 + 16*d] = make_float2(Xr, Xi);
    }
}

template<int SIGNPOS, int REALOUT, int SCALE>
__global__ void __launch_bounds__(256) k_fft_cols(const float2* in, float2* outc, float* outr){
    const float sgn = SIGNPOS ? 1.0f : -1.0f;
    __shared__ float tre[N*17];
    __shared__ float tim_[N*17];
    __shared__ float zre[8*16*17];
    __shared__ float zim[8*16*17];
    int t = threadIdx.x;
    int img = blockIdx.x >> 3; int x0 = (blockIdx.x & 7)*16;
    const float2* src = in + (size_t)img*N*N + x0;
    #pragma unroll
    for(int j=0;j<8;j++){
        int idx = t + 256*j; int y = idx>>4, xc = idx&15;
        float2 v = src[y*N + xc];
        tre[y*17+xc]=v.x; tim_[y*17+xc]=v.y;
    }
    float t16c[16], t16s[16];
    #pragma unroll
    for(int j=0;j<16;j++){ float s,c; sincosf(sgn*(TWO_PI_F/16.f)*(float)j, &s,&c); t16c[j]=c; t16s[j]=s; }
    __syncthreads();

    int xc = t&15, u = t>>4, b = u&7, h = u>>3;
    float xr[16], xi[16];
    #pragma unroll
    for(int a=0;a<16;a++){
        int y = 8*a + b;
        float vr = tre[y*17+xc];
        float vi = tim_[y*17+xc];
        if(h && (a&1)){ vr = -vr; vi = -vi; }
        xr[a]=vr; xi[a]=vi;
    }
    #pragma unroll
    for(int cc=0; cc<8; cc++){
        float yr=0.f, yi=0.f;
        #pragma unroll
        for(int a=0;a<16;a++){
            int j = (a*cc)&15;
            yr = fmaf(xr[a], t16c[j], yr); yr = fmaf(-xi[a], t16s[j], yr);
            yi = fmaf(xr[a], t16s[j], yi); yi = fmaf( xi[a], t16c[j], yi);
        }
        int c = 8*h + cc;
        float s,co; sincosf(sgn*(TWO_PI_F/128.f)*(float)(b*c), &s,&co);
        zre[(b*16 + c)*17 + xc] = fmaf(yr,co,-(yi*s));
        zim[(b*16 + c)*17 + xc] = fmaf(yr,s,  yi*co);
    }
    __syncthreads();

    float t8c[8], t8s[8];
    #pragma unroll
    for(int j=0;j<8;j++){ float s,c; sincosf(sgn*(TWO_PI_F/8.f)*(float)j, &s,&c); t8c[j]=c; t8s[j]=s; }
    int c2 = t>>4; int x2 = t&15;
    float zr_[8], zi_[8];
    #pragma unroll
    for(int bb=0;bb<8;bb++){ zr_[bb]=zre[(bb*16 + c2)*17 + x2]; zi_[bb]=zim[(bb*16 + c2)*17 + x2]; }
    #pragma unroll
    for(int d=0; d<8; d++){
        float Xr=0.f, Xi=0.f;
        #pragma unroll
        for(int bb=0;bb<8;bb++){
            int j=(bb*d)&7;
            Xr = fmaf(zr_[bb], t8c[j], Xr); Xr = fmaf(-zi_[bb], t8s[j], Xr);
            Xi = fmaf(zr_[bb], t8s[j], Xi); Xi = fmaf( zi_[bb], t8c[j], Xi);
        }
        int ky = c2 + 16*d;
        if(REALOUT){
            outr[(size_t)img*N*N + ky*N + x0 + x2] = Xr * (SCALE ? (1.f/128.f) : 1.f);
        } else {
            if(SCALE){ Xr *= (1.f/128.f); Xi *= (1.f/128.f); }
            outc[(size_t)img*N*N + ky*N + x0 + x2] = make_float2(Xr, Xi);
        }
    }
}

// res1[b,k,o,x] = sum_i alpha[b,i,o,x] * sum_p A1T[o][ik,p] * W2N[ik,p][x]
__global__ void __launch_bounds__(256) k_res1(const float2* alpha, const float2* A1T,
                                              const float2* W2N, float2* res1){
    __shared__ float4 At4[B*CI*8];   // [img][xq] , xq = x-pair; 32 KB
    int t = threadIdx.x;
    int o  = blockIdx.x >> 3;
    int x0 = (blockIdx.x & 7) * 16;

    {
        int im0 = t >> 3, xq = t & 7;
        #pragma unroll
        for(int j=0;j<8;j++){
            int im = im0 + 32*j;
            At4[im*8 + xq] = *(const float4*)(alpha + (size_t)im*(N*N) + o*N + x0 + 2*xq);
        }
    }
    __syncthreads();

    int k = t >> 3, xh = t & 7;
    float2 acc[B][2];
    #pragma unroll
    for(int b=0;b<B;b++){ acc[b][0]=make_float2(0.f,0.f); acc[b][1]=make_float2(0.f,0.f); }

    const float2* a1base = A1T + (size_t)o*IKP + k*M1;            // + i*128
    const float2* w2base = W2N + ((size_t)k*M1)*N + x0 + 2*xh;    // + i*128*N + p*N

    #pragma unroll 2
    for(int i=0;i<CI;i++){
        float4 a1a = *(const float4*)(a1base + (size_t)i*128);
        float4 a1b = *(const float4*)(a1base + (size_t)i*128 + 2);
        float2 a1v[M1] = { make_float2(a1a.x,a1a.y), make_float2(a1a.z,a1a.w),
                           make_float2(a1b.x,a1b.y), make_float2(a1b.z,a1b.w) };
        float2 h0 = make_float2(0.f,0.f), h1 = make_float2(0.f,0.f);
        const float2* w2 = w2base + (size_t)i*(128*N);
        #pragma unroll
        for(int p=0;p<M1;p++){
            float4 wv = *(const float4*)(w2 + (size_t)p*N);
            h0 = cmadd(h0, a1v[p], make_float2(wv.x,wv.y));
            h1 = cmadd(h1, a1v[p], make_float2(wv.z,wv.w));
        }
        #pragma unroll
        for(int b=0;b<B;b++){
            float4 av = At4[(b*CI + i)*8 + xh];
            acc[b][0] = cmadd(acc[b][0], make_float2(av.x,av.y), h0);
            acc[b][1] = cmadd(acc[b][1], make_float2(av.z,av.w), h1);
        }
    }

    #pragma unroll
    for(int b=0;b<B;b++){
        float4 v = make_float4(acc[b][0].x, acc[b][0].y, acc[b][1].x, acc[b][1].y);
        *(float4*)(res1 + (size_t)(b*CO + k)*(N*N) + o*N + x0 + 2*xh) = v;
    }
}

// per (b, i, oh, xh): grid 1024 x 512 thr = 4 blocks/CU co-resident (2048 thr = HW max).
// Round-7 register structure UNCHANGED (U[4][5], S[4][5], natural VGPR=64 — must not exceed).
// Block: o-half (64 o's) x x-half (64 x's, 8 chunks of 8). LDS 14.8 KB (4x = 59 KB fits).
// Partials to part[...4 slices], no atomics.
__global__ void __launch_bounds__(512) k_S_res2(const float2* alpha, const float2* A2,
                                                const float2* A1T, float2* part){
    __shared__ float2 tile[64*9];     // alpha chunk [o-row][xc<8], pad 9
    __shared__ float2 A2c[8*160];     // [xc][kl*5+q] (broadcast reads)
    int t = threadIdx.x;
    int ol = t & 15;
    int kl = t >> 4;                  // 0..31 = k
    int bid = blockIdx.x;             // ((b*CI + i)*2 + oh)*2 + xh
    int xh = bid & 1;
    int oh = (bid >> 1) & 1;
    int i  = (bid >> 2) & (CI-1);
    int b  = bid >> 7;
    int ik = i*CO + kl;
    const int XB = xh*64;
    const float2* asrc = alpha + ((size_t)(b*CI + i))*(N*N) + (size_t)oh*64*N + XB;

    const int trow = t >> 3, txc = t & 7;    // alpha staging: 64 rows x 8 cols, 1 elem/thread
    int a2dst[3]; size_t a2src[3]; bool a2ok[3];
    #pragma unroll
    for(int s=0;s<3;s++){
        int e = t + 512*s;                    // 1280 = 8*160 total
        a2ok[s] = (e < 1280);
        int e2 = a2ok[s] ? e : 0;
        int xcs = e2 / 160, rs = e2 - xcs*160;
        int kk = rs / 5, qq = rs - kk*5;
        a2dst[s] = e2;
        a2src[s] = ((size_t)(i*CO + kk)*M2 + qq)*N + XB + xcs;
    }

    float2 U[4][5];                           // [oi][q]
    #pragma unroll
    for(int oi=0;oi<4;oi++)
        #pragma unroll
        for(int q=0;q<5;q++) U[oi][q] = make_float2(0.f,0.f);

    float2 pre, a2pre[3];
    pre = asrc[trow*N + txc];
    #pragma unroll
    for(int s=0;s<3;s++) if(a2ok[s]) a2pre[s] = A2[a2src[s]];

    for(int c=0; c<8; c++){
        __syncthreads();
        tile[trow*9 + txc] = pre;
        #pragma unroll
        for(int s=0;s<3;s++) if(a2ok[s]) A2c[a2dst[s]] = a2pre[s];
        if(c < 7){
            int x0n = (c+1)*8;
            pre = asrc[trow*N + x0n + txc];
            #pragma unroll
            for(int s=0;s<3;s++) if(a2ok[s]) a2pre[s] = A2[a2src[s] + x0n];
        }
        __syncthreads();
        #pragma unroll
        for(int xc=0; xc<8; xc++){
            float2 a2v[5];
            const float2* a2row = A2c + xc*160 + kl*5;
            #pragma unroll
            for(int q=0;q<5;q++) a2v[q] = a2row[q];
            #pragma unroll
            for(int oi=0;oi<4;oi++){
                float2 av = tile[(ol + 16*oi)*9 + xc];
                #pragma unroll
                for(int q=0;q<5;q++) U[oi][q] = cmadd(U[oi][q], av, a2v[q]);
            }
        }
    }

    // S-phase: S[p][q] = sum_{o in this half} A1[ik,p,o]*U[o][q]; 16-lane butterfly
    float2 S[4][5];
    #pragma unroll
    for(int p=0;p<4;p++)
        #pragma unroll
        for(int q=0;q<5;q++) S[p][q] = make_float2(0.f,0.f);
    #pragma unroll
    for(int oi=0;oi<4;oi++){
        int o = oh*64 + ol + 16*oi;
        const float2* a1 = A1T + (size_t)o*IKP + (size_t)ik*M1;
        float2 a1v[4];
        #pragma unroll
        for(int p=0;p<4;p++) a1v[p] = a1[p];
        #pragma unroll
        for(int p=0;p<4;p++)
            #pragma unroll
            for(int q=0;q<5;q++) S[p][q] = cmadd(S[p][q], a1v[p], U[oi][q]);
    }
    #pragma unroll
    for(int m=1;m<16;m<<=1){
        #pragma unroll
        for(int p=0;p<4;p++)
            #pragma unroll
            for(int q=0;q<5;q++){
                S[p][q].x += __shfl_xor(S[p][q].x, m);
                S[p][q].y += __shfl_xor(S[p][q].y, m);
            }
    }
    if(ol==0){
        float2* dst = part + ((size_t)((b*CO + kl)*CI + i)*4 + oh*2 + xh)*(M1*M2);
        #pragma unroll
        for(int p=0;p<4;p++)
            #pragma unroll
            for(int q=0;q<5;q++) dst[p*5+q] = S[p][q];
    }
}

// res2[bk][pq] = sum_i w[i*CO+k][pq] * sum_s part[(bk*CI+i)*4+s][pq]
// 256 blocks (bk) x 128 thr (i = t&31, g = t>>5 covers 5 pq); shuffle-reduce over i.
__global__ void k_res2_red(const float2* part, const float* wrr, const float* wri, float2* res2){
    int bk = blockIdx.x;
    int t = threadIdx.x;
    int i = t & 31, g = t >> 5;
    int k = bk & (CO-1);
    int ikk = i*CO + k;
    float2 acc[5];
    #pragma unroll
    for(int e=0;e<5;e++){
        int pq = g*5 + e;
        float2 w = make_float2(wrr[ikk*(M1*M2)+pq], wri[ikk*(M1*M2)+pq]);
        const float2* pp = part + ((size_t)(bk*CI + i)*4)*(M1*M2) + pq;
        float2 s0 = pp[0], s1 = pp[M1*M2], s2 = pp[2*M1*M2], s3 = pp[3*M1*M2];
        float2 s = make_float2(s0.x+s1.x+s2.x+s3.x, s0.y+s1.y+s2.y+s3.y);
        acc[e] = cmul(w, s);
    }
    #pragma unroll
    for(int m=1;m<32;m<<=1){
        #pragma unroll
        for(int e=0;e<5;e++){
            acc[e].x += __shfl_xor(acc[e].x, m);
            acc[e].y += __shfl_xor(acc[e].y, m);
        }
    }
    if(i==0){
        #pragma unroll
        for(int e=0;e<5;e++) res2[(size_t)bk*(M1*M2) + g*5 + e] = acc[e];
    }
}

// x2[b,j,y,x] += (1/N^2) * Re( sum_{c,p,q} res2[b,c,p,q]*E1[c,j,p,y]*E2[c,j,q,x] )
// grid = (b, j, yh): 512 blocks (2/CU); 256 thr = 16 yt x 16 xt; thread tile 4y x 8x.
__global__ void __launch_bounds__(256) k_x2(const float2* res2, const float2* E1,
                                            const float2* E2, float* out){
    __shared__ __align__(16) float2 res2s[CI*M1*M2];        // 640
    __shared__ __align__(16) float2 Wt[M1*N];               // 512
    __shared__ __align__(16) float2 buf[2][M1*64 + M2*N];   // 896 each: E1s[0,256) + E2s[256,896)
    int t = threadIdx.x;
    int yh = blockIdx.x & 1;
    int j  = (blockIdx.x >> 1) & (CO-1);
    int b  = blockIdx.x >> 6;
    int xt = t & 15, yt = t >> 4;

    // stage res2 for this b: 640 float2 = 320 float4, contiguous
    {
        const float4* s4 = (const float4*)(res2 + (size_t)b*CO*M1*M2);
        float4* d4 = (float4*)res2s;
        d4[t] = s4[t];
        if(t < 64) d4[256+t] = s4[256+t];
    }

    // staging slots: slot0 = e=t (E1 if t<128 else E2), slot1 = e=t+256 (E2, t<192)
    const bool is1_0 = (t < 128);
    const bool ok1 = (t < 192);
    int off0, dst0;
    if(is1_0){ int pp = t >> 5, rem = (t & 31) << 1; off0 = pp*N + rem; dst0 = pp*64 + rem; }
    else     { int g = t - 128; int qq = g >> 6, xi = (g & 63) << 1; off0 = qq*N + xi; dst0 = 256 + qq*128 + xi; }
    int g1 = t + 128; int qq1 = g1 >> 6, xi1 = (g1 & 63) << 1;
    int off1 = qq1*N + xi1;
    int dst1 = 256 + qq1*128 + xi1;

    const float2* E1c = E1 + ((size_t)j*M1)*N + yh*64;   // advances by CO*M1*N per c
    const float2* E2c = E2 + ((size_t)j*M2)*N;           // advances by CO*M2*N per c

    // preload c=0 and commit to buf[0]
    float4 pre0 = *(const float4*)((is1_0 ? E1c : E2c) + off0);
    float4 pre1 = ok1 ? *(const float4*)(E2c + off1) : make_float4(0.f,0.f,0.f,0.f);
    *(float4*)(&buf[0][dst0]) = pre0;
    if(ok1) *(float4*)(&buf[0][dst1]) = pre1;
    int cur = 0;
    __syncthreads();

    float acc[4][8];
    #pragma unroll
    for(int yy=0;yy<4;yy++)
        #pragma unroll
        for(int s=0;s<8;s++) acc[yy][s] = 0.f;

    for(int c=0; c<CI; c++){
        // ---- Wt compute: 512 elems, 2/thread, from E2s[cur] + res2s ----
        const float2* E2s = buf[cur] + 256;
        #pragma unroll
        for(int s=0;s<2;s++){
            int e = t + 256*s;
            int pp = e >> 7, xi = e & 127;
            const float2* rr = res2s + c*(M1*M2) + pp*M2;
            float2 w = make_float2(0.f,0.f);
            #pragma unroll
            for(int q=0;q<M2;q++) w = cmadd(w, rr[q], E2s[q*128 + xi]);
            Wt[pp*128 + xi] = w;
        }
        // ---- issue prefetch of c+1 (consumed after compute) ----
        if(c+1 < CI){
            E1c += (size_t)CO*M1*N;
            E2c += (size_t)CO*M2*N;
            pre0 = *(const float4*)((is1_0 ? E1c : E2c) + off0);
            if(ok1) pre1 = *(const float4*)(E2c + off1);
        }
        __syncthreads();   // Wt visible; E2s[cur] reads done

        // ---- acc compute: 4y x 8x tile ----
        const float2* E1s = buf[cur];
        #pragma unroll
        for(int p=0;p<4;p++){
            float2 e1[4];
            float4 a  = *(const float4*)(E1s + p*64 + yt*4);
            float4 bq = *(const float4*)(E1s + p*64 + yt*4 + 2);
            e1[0]=make_float2(a.x,a.y);  e1[1]=make_float2(a.z,a.w);
            e1[2]=make_float2(bq.x,bq.y); e1[3]=make_float2(bq.z,bq.w);
            #pragma unroll
            for(int s=0;s<4;s++){
                float4 wv = *(const float4*)(Wt + p*128 + 32*s + 2*xt);
                #pragma unroll
                for(int yy=0;yy<4;yy++){
                    float2 e = e1[yy];
                    acc[yy][2*s]   = fmaf(e.x, wv.x, fmaf(-e.y, wv.y, acc[yy][2*s]));
                    acc[yy][2*s+1] = fmaf(e.x, wv.z, fmaf(-e.y, wv.w, acc[yy][2*s+1]));
                }
            }
        }
        // ---- commit prefetched tile to the other buffer ----
        if(c+1 < CI){
            float2* nb = buf[cur^1];
            *(float4*)(nb + dst0) = pre0;
            if(ok1) *(float4*)(nb + dst1) = pre1;
        }
        cur ^= 1;
        __syncthreads();   // next-buf writes visible; Wt reads done before next overwrite
    }

    const float sc = 1.0f/((float)N*(float)N);
    size_t base = (size_t)(b*CO + j)*(N*N) + (size_t)yh*64*N;
    #pragma unroll
    for(int yy=0;yy<4;yy++){
        float* orow = out + base + (size_t)(yt*4 + yy)*N;
        #pragma unroll
        for(int s=0;s<4;s++){
            float2* dst = (float2*)(orow + 32*s + 2*xt);
            float2 old = *dst;
            *dst = make_float2(old.x + acc[yy][2*s]*sc, old.y + acc[yy][2*s+1]*sc);
        }
    }
}

extern "C" void kernel_launch(void* const* d_in, const int* in_sizes, int n_in,
                              void* d_out, int out_size, void* d_ws, size_t ws_size,
                              hipStream_t stream){
    const float* x    = (const float*)d_in[0];
    const float* wp1r = (const float*)d_in[1];
    const float* wp1i = (const float*)d_in[2];
    const float* wp2r = (const float*)d_in[3];
    const float* wp2i = (const float*)d_in[4];
    const float* wrr  = (const float*)d_in[5];
    const float* wri  = (const float*)d_in[6];
    const float* ty   = (const float*)d_in[7];
    const float* tx   = (const float*)d_in[8];
    float* out = (float*)d_out;
    float2* ws = (float2*)d_ws;

    const size_t NCIMG = (size_t)B*CI*N*N;        // 4194304 complexes
    float2* bufA  = ws;
    float2* alpha = bufA  + NCIMG;
    float2* res1  = alpha + NCIMG;
    float2* A1T   = res1  + NCIMG;                // N*IKP
    float2* A2    = A1T   + (size_t)N*IKP;        // IKQ*N
    float2* W2N   = A2    + (size_t)IKQ*N;        // IKP*N (natural layout [ikp][x])
    float2* E1    = W2N   + (size_t)N*IKP;        // IKP*N
    float2* E2    = E1    + (size_t)IKP*N;        // IKQ*N
    float2* res2  = E2    + (size_t)IKQ*N;        // B*CO*M1*M2
    float2* part  = res2  + (size_t)B*CO*M1*M2;   // B*CO*CI*4*M1*M2 = 655360

    k_A1T<<<(N*IKP)/256, 256, 0, stream>>>(wp1r, wp1i, ty, A1T);
    k_E  <<<(IKP*N)/256, 256, 0, stream>>>(wp1r, wp1i, ty, E1);
    k_A2 <<<(IKQ*N)/256, 256, 0, stream>>>(wp2r, wp2i, tx, A2);
    k_E  <<<(IKQ*N)/256, 256, 0, stream>>>(wp2r, wp2i, tx, E2);
    k_W2N<<<(IKP*N)/256, 256, 0, stream>>>(wrr, wri, A2, W2N);

    // forward fft2: rows (real in) then cols
    k_fft_rows<0,1,0><<<(B*CI*N)/16, 256, 0, stream>>>((const void*)x, bufA);
    k_fft_cols<0,0,0><<<B*CI*8, 256, 0, stream>>>(bufA, alpha, nullptr);

    k_res1<<<N*8, 256, 0, stream>>>(alpha, A1T, W2N, res1);
    k_S_res2<<<B*CI*4, 512, 0, stream>>>(alpha, A2, A1T, part);
    k_res2_red<<<B*CO, 128, 0, stream>>>(part, wrr, wri, res2);

    // inverse fft2: rows (1/N) then cols (real out, 1/N)
    k_fft_rows<1,0,1><<<(B*CO*N)/16, 256, 0, stream>>>((const void*)res1, bufA);
    k_fft_cols<1,1,1><<<B*CO*8, 256, 0, stream>>>(bufA, nullptr, out);
    k_x2<<<B*CO*2, 256, 0, stream>>>(res2, E1, E2, out);
}

// Round 9
// 310.358 us; speedup vs baseline: 1.0395x; 1.0395x over previous
//
#include <hip/hip_runtime.h>
#include <math.h>

#define N 128
#define B 8
#define CI 32
#define CO 32
#define M1 4
#define M2 5
#define IK (CI*CO)       // 1024
#define IKP (IK*M1)      // 4096
#define IKQ (IK*M2)      // 5120
#define TWO_PI_F 6.2831853071795864769f

// 4 v_fma per cmadd, guaranteed
__device__ __forceinline__ float2 cmul(float2 a, float2 b){
    return make_float2(fmaf(a.x,b.x,-(a.y*b.y)), fmaf(a.x,b.y,a.y*b.x));
}
__device__ __forceinline__ float2 cmadd(float2 acc, float2 a, float2 b){
    acc.x = fmaf(a.x, b.x, fmaf(-a.y, b.y, acc.x));
    acc.y = fmaf(a.x, b.y, fmaf( a.y, b.x, acc.y));
    return acc;
}

// A1T[o][ik*M1+p] = 1/(i*2pi*f(o) - wp1[ik,p]); freq-major for contiguous per-o slices
__global__ void k_A1T(const float* wr_, const float* wi_, const float* t_, float2* A1T){
    int idx = blockIdx.x*256 + threadIdx.x;      // [0, N*IKP)
    int o   = idx >> 12;                          // /IKP
    int ikp = idx & (IKP-1);
    float d = t_[1]-t_[0];
    float invnd = 1.0f/((float)N*d);
    int kk = (o < N/2) ? o : o - N;
    float lam = TWO_PI_F * (float)kk * invnd;
    float dr = -wr_[ikp];
    float di = lam - wi_[ikp];
    float inv = 1.0f/(dr*dr + di*di);
    A1T[idx] = make_float2(dr*inv, -di*inv);
}

// A2[ikq][x] natural layout
__global__ void k_A2(const float* wr_, const float* wi_, const float* t_, float2* A2){
    int idx = blockIdx.x*256 + threadIdx.x;      // [0, IKQ*N)
    int ikq = idx >> 7; int xx = idx & (N-1);
    float d = t_[1]-t_[0];
    float invnd = 1.0f/((float)N*d);
    int kk = (xx < N/2) ? xx : xx - N;
    float lam = TWO_PI_F * (float)kk * invnd;
    float dr = -wr_[ikq];
    float di = lam - wi_[ikq];
    float inv = 1.0f/(dr*dr + di*di);
    A2[idx] = make_float2(dr*inv, -di*inv);
}

// E[ikp][y] = exp(wp[ikp] * t[y])
__global__ void k_E(const float* wr_, const float* wi_, const float* t_, float2* E){
    int idx = blockIdx.x*256 + threadIdx.x;
    int ikp = idx >> 7; int y = idx & (N-1);
    float t = t_[y];
    float m = expf(wr_[ikp]*t);
    float s, c; sincosf(wi_[ikp]*t, &s, &c);
    E[idx] = make_float2(m*c, m*s);
}

// W2N[ikp][x] = sum_q wr[ik,p,q] * A2[ik,q,x]   (natural layout; coalesced store)
__global__ void k_W2N(const float* wrr, const float* wri, const float2* A2, float2* W2N){
    int idx = blockIdx.x*256 + threadIdx.x;      // [0, IKP*N)
    int ikp = idx >> 7; int xx = idx & (N-1);
    int ik = ikp >> 2; int p = ikp & 3;
    float2 acc = make_float2(0.f,0.f);
    const float* wr0 = wrr + ik*(M1*M2) + p*M2;
    const float* wi0 = wri + ik*(M1*M2) + p*M2;
    const float2* a2 = A2 + (size_t)ik*(M2*N) + xx;
    #pragma unroll
    for(int q=0;q<M2;q++){
        float2 w = make_float2(wr0[q], wi0[q]);
        acc = cmadd(acc, w, a2[q*N]);
    }
    W2N[(size_t)ikp*N + xx] = acc;
}

// ---------- four-step FFT, 128 = 16 x 8 ----------
template<int SIGNPOS, int REALIN, int SCALE>
__global__ void __launch_bounds__(256) k_fft_rows(const void* in_, float2* out){
    const float sgn = SIGNPOS ? 1.0f : -1.0f;
    __shared__ float tre[16*132];
    __shared__ float tim_[16*132];
    __shared__ float zre[16*136];
    __shared__ float zim[16*136];
    int t = threadIdx.x;
    size_t row0 = (size_t)blockIdx.x * 16;

    if(REALIN){
        const float* src = (const float*)in_ + row0*N;
        #pragma unroll
        for(int j=0;j<8;j++){
            int idx = t + 256*j; int r = idx>>7, cl = idx&127;
            tre[r*132+cl] = src[idx];
        }
    } else {
        const float2* src = (const float2*)in_ + row0*N;
        #pragma unroll
        for(int j=0;j<8;j++){
            int idx = t + 256*j; int r = idx>>7, cl = idx&127;
            float2 v = src[idx];
            tre[r*132+cl] = v.x; tim_[r*132+cl] = v.y;
        }
    }
    float t16c[16], t16s[16];
    #pragma unroll
    for(int j=0;j<16;j++){ float s,c; sincosf(sgn*(TWO_PI_F/16.f)*(float)j, &s,&c); t16c[j]=c; t16s[j]=s; }
    __syncthreads();

    int r = t>>4, u = t&15, b = u&7, h = u>>3;
    float xr[16], xi[16];
    #pragma unroll
    for(int a=0;a<16;a++){
        float vr = tre[r*132 + 8*a + b];
        float vi = REALIN ? 0.f : tim_[r*132 + 8*a + b];
        if(h && (a&1)){ vr = -vr; vi = -vi; }
        xr[a]=vr; xi[a]=vi;
    }
    #pragma unroll
    for(int cc=0; cc<8; cc++){
        float yr=0.f, yi=0.f;
        #pragma unroll
        for(int a=0;a<16;a++){
            int j = (a*cc)&15;
            if(REALIN){
                yr = fmaf(xr[a], t16c[j], yr);
                yi = fmaf(xr[a], t16s[j], yi);
            } else {
                yr = fmaf(xr[a], t16c[j], yr); yr = fmaf(-xi[a], t16s[j], yr);
                yi = fmaf(xr[a], t16s[j], yi); yi = fmaf( xi[a], t16c[j], yi);
            }
        }
        int c = 8*h + cc;
        float s,co; sincosf(sgn*(TWO_PI_F/128.f)*(float)(b*c), &s,&co);
        zre[r*136 + b*17 + c] = fmaf(yr,co,-(yi*s));
        zim[r*136 + b*17 + c] = fmaf(yr,s,  yi*co);
    }
    __syncthreads();

    float t8c[8], t8s[8];
    #pragma unroll
    for(int j=0;j<8;j++){ float s,c; sincosf(sgn*(TWO_PI_F/8.f)*(float)j, &s,&c); t8c[j]=c; t8s[j]=s; }
    int r2 = t>>4, c2 = t&15;
    float zr_[8], zi_[8];
    #pragma unroll
    for(int bb=0;bb<8;bb++){ zr_[bb]=zre[r2*136 + bb*17 + c2]; zi_[bb]=zim[r2*136 + bb*17 + c2]; }
    float2* dst = out + (row0 + r2)*N;
    #pragma unroll
    for(int d=0; d<8; d++){
        float Xr=0.f, Xi=0.f;
        #pragma unroll
        for(int bb=0;bb<8;bb++){
            int j=(bb*d)&7;
            Xr = fmaf(zr_[bb], t8c[j], Xr); Xr = fmaf(-zi_[bb], t8s[j], Xr);
            Xi = fmaf(zr_[bb], t8s[j], Xi); Xi = fmaf( zi_[bb], t8c[j], Xi);
        }
        if(SCALE){ Xr *= (1.f/128.f); Xi *= (1.f/128.f); }
        dst[c2 + 16*d] = make_float2(Xr, Xi);
    }
}

template<int SIGNPOS, int REALOUT, int SCALE>
__global__ void __launch_bounds__(256) k_fft_cols(const float2* in, float2* outc, float* outr){
    const float sgn = SIGNPOS ? 1.0f : -1.0f;
    __shared__ float tre[N*17];
    __shared__ float tim_[N*17];
    __shared__ float zre[8*16*17];
    __shared__ float zim[8*16*17];
    int t = threadIdx.x;
    int img = blockIdx.x >> 3; int x0 = (blockIdx.x & 7)*16;
    const float2* src = in + (size_t)img*N*N + x0;
    #pragma unroll
    for(int j=0;j<8;j++){
        int idx = t + 256*j; int y = idx>>4, xc = idx&15;
        float2 v = src[y*N + xc];
        tre[y*17+xc]=v.x; tim_[y*17+xc]=v.y;
    }
    float t16c[16], t16s[16];
    #pragma unroll
    for(int j=0;j<16;j++){ float s,c; sincosf(sgn*(TWO_PI_F/16.f)*(float)j, &s,&c); t16c[j]=c; t16s[j]=s; }
    __syncthreads();

    int xc = t&15, u = t>>4, b = u&7, h = u>>3;
    float xr[16], xi[16];
    #pragma unroll
    for(int a=0;a<16;a++){
        int y = 8*a + b;
        float vr = tre[y*17+xc];
        float vi = tim_[y*17+xc];
        if(h && (a&1)){ vr = -vr; vi = -vi; }
        xr[a]=vr; xi[a]=vi;
    }
    #pragma unroll
    for(int cc=0; cc<8; cc++){
        float yr=0.f, yi=0.f;
        #pragma unroll
        for(int a=0;a<16;a++){
            int j = (a*cc)&15;
            yr = fmaf(xr[a], t16c[j], yr); yr = fmaf(-xi[a], t16s[j], yr);
            yi = fmaf(xr[a], t16s[j], yi); yi = fmaf( xi[a], t16c[j], yi);
        }
        int c = 8*h + cc;
        float s,co; sincosf(sgn*(TWO_PI_F/128.f)*(float)(b*c), &s,&co);
        zre[(b*16 + c)*17 + xc] = fmaf(yr,co,-(yi*s));
        zim[(b*16 + c)*17 + xc] = fmaf(yr,s,  yi*co);
    }
    __syncthreads();

    float t8c[8], t8s[8];
    #pragma unroll
    for(int j=0;j<8;j++){ float s,c; sincosf(sgn*(TWO_PI_F/8.f)*(float)j, &s,&c); t8c[j]=c; t8s[j]=s; }
    int c2 = t>>4; int x2 = t&15;
    float zr_[8], zi_[8];
    #pragma unroll
    for(int bb=0;bb<8;bb++){ zr_[bb]=zre[(bb*16 + c2)*17 + x2]; zi_[bb]=zim[(bb*16 + c2)*17 + x2]; }
    #pragma unroll
    for(int d=0; d<8; d++){
        float Xr=0.f, Xi=0.f;
        #pragma unroll
        for(int bb=0;bb<8;bb++){
            int j=(bb*d)&7;
            Xr = fmaf(zr_[bb], t8c[j], Xr); Xr = fmaf(-zi_[bb], t8s[j], Xr);
            Xi = fmaf(zr_[bb], t8s[j], Xi); Xi = fmaf( zi_[bb], t8c[j], Xi);
        }
        int ky = c2 + 16*d;
        if(REALOUT){
            outr[(size_t)img*N*N + ky*N + x0 + x2] = Xr * (SCALE ? (1.f/128.f) : 1.f);
        } else {
            if(SCALE){ Xr *= (1.f/128.f); Xi *= (1.f/128.f); }
            outc[(size_t)img*N*N + ky*N + x0 + x2] = make_float2(Xr, Xi);
        }
    }
}

// res1[b,k,o,x] = sum_i alpha[b,i,o,x] * sum_p A1T[o][ik,p] * W2N[ik,p][x]
__global__ void __launch_bounds__(256) k_res1(const float2* alpha, const float2* A1T,
                                              const float2* W2N, float2* res1){
    __shared__ float4 At4[B*CI*8];   // [img][xq] , xq = x-pair; 32 KB
    int t = threadIdx.x;
    int o  = blockIdx.x >> 3;
    int x0 = (blockIdx.x & 7) * 16;

    {
        int im0 = t >> 3, xq = t & 7;
        #pragma unroll
        for(int j=0;j<8;j++){
            int im = im0 + 32*j;
            At4[im*8 + xq] = *(const float4*)(alpha + (size_t)im*(N*N) + o*N + x0 + 2*xq);
        }
    }
    __syncthreads();

    int k = t >> 3, xh = t & 7;
    float2 acc[B][2];
    #pragma unroll
    for(int b=0;b<B;b++){ acc[b][0]=make_float2(0.f,0.f); acc[b][1]=make_float2(0.f,0.f); }

    const float2* a1base = A1T + (size_t)o*IKP + k*M1;            // + i*128
    const float2* w2base = W2N + ((size_t)k*M1)*N + x0 + 2*xh;    // + i*128*N + p*N

    #pragma unroll 2
    for(int i=0;i<CI;i++){
        float4 a1a = *(const float4*)(a1base + (size_t)i*128);
        float4 a1b = *(const float4*)(a1base + (size_t)i*128 + 2);
        float2 a1v[M1] = { make_float2(a1a.x,a1a.y), make_float2(a1a.z,a1a.w),
                           make_float2(a1b.x,a1b.y), make_float2(a1b.z,a1b.w) };
        float2 h0 = make_float2(0.f,0.f), h1 = make_float2(0.f,0.f);
        const float2* w2 = w2base + (size_t)i*(128*N);
        #pragma unroll
        for(int p=0;p<M1;p++){
            float4 wv = *(const float4*)(w2 + (size_t)p*N);
            h0 = cmadd(h0, a1v[p], make_float2(wv.x,wv.y));
            h1 = cmadd(h1, a1v[p], make_float2(wv.z,wv.w));
        }
        #pragma unroll
        for(int b=0;b<B;b++){
            float4 av = At4[(b*CI + i)*8 + xh];
            acc[b][0] = cmadd(acc[b][0], make_float2(av.x,av.y), h0);
            acc[b][1] = cmadd(acc[b][1], make_float2(av.z,av.w), h1);
        }
    }

    #pragma unroll
    for(int b=0;b<B;b++){
        float4 v = make_float4(acc[b][0].x, acc[b][0].y, acc[b][1].x, acc[b][1].y);
        *(float4*)(res1 + (size_t)(b*CO + k)*(N*N) + o*N + x0 + 2*xh) = v;
    }
}

// per (b, i, oh): grid 512 x 512 thr. VGPR-capped regime (64 VGPR -> 4 waves/SIMD,
// 2 blocks/CU) — so spend LDS freely: x-chunk 32, LDS 59 KB, barriers 32 -> 8.
// tile[64][33] alpha rows (2-way bank, free); A2c[160][33] row-major so staging
// reads are coalesced 256B row segments (old [xc][r] map scattered 64x8B).
// Register structure identical to round 7 (U[4][5], S[4][5]); (512,4) pins VGPR=64.
__global__ void __launch_bounds__(512, 4) k_S_res2(const float2* alpha, const float2* A2,
                                                   const float2* A1T, float2* part){
    __shared__ float2 tile[64*33];    // [o-row][xc<32], pad 33
    __shared__ float2 A2c[160*33];    // [row = kk*5+q][xc], pad 33
    int t = threadIdx.x;
    int ol = t & 15;
    int kl = t >> 4;                  // 0..31 = k
    int bid = blockIdx.x;             // (b*CI + i)*2 + oh
    int oh = bid & 1;
    int i  = (bid >> 1) & (CI-1);
    int b  = bid >> 6;
    int ik = i*CO + kl;
    const float2* asrc = alpha + ((size_t)(b*CI + i))*(N*N) + (size_t)oh*64*N;
    const float2* a2base = A2 + (size_t)i*(CO*M2*N);   // row r -> + r*N

    // staging maps: txc = col 0..31 (coalesced), trow/srow = row groups
    const int txc = t & 31, trow = t >> 5;   // alpha: rows trow+16j (j<4)
    float2 U[4][5];                           // [oi][q]
    #pragma unroll
    for(int oi=0;oi<4;oi++)
        #pragma unroll
        for(int q=0;q<5;q++) U[oi][q] = make_float2(0.f,0.f);

    float2 pre[4];
    #pragma unroll
    for(int j=0;j<4;j++) pre[j] = asrc[(trow + 16*j)*N + txc];

    for(int c=0; c<4; c++){
        __syncthreads();   // previous chunk's compute done
        #pragma unroll
        for(int j=0;j<4;j++) tile[(trow + 16*j)*33 + txc] = pre[j];
        // A2 direct stage: 160 rows x 32 cols = 10 rows/thread-group, coalesced source
        #pragma unroll
        for(int s=0;s<10;s++){
            int rs = s*16 + trow;             // 0..159
            A2c[rs*33 + txc] = a2base[(size_t)rs*N + c*32 + txc];
        }
        if(c < 3){
            #pragma unroll
            for(int j=0;j<4;j++) pre[j] = asrc[(trow + 16*j)*N + (c+1)*32 + txc];
        }
        __syncthreads();
        #pragma unroll 4
        for(int xc=0; xc<32; xc++){
            float2 a2v[5];
            const float2* a2row = A2c + (kl*5)*33 + xc;
            #pragma unroll
            for(int q=0;q<5;q++) a2v[q] = a2row[q*33];
            #pragma unroll
            for(int oi=0;oi<4;oi++){
                float2 av = tile[(ol + 16*oi)*33 + xc];
                #pragma unroll
                for(int q=0;q<5;q++) U[oi][q] = cmadd(U[oi][q], av, a2v[q]);
            }
        }
    }

    // S-phase: S[p][q] = sum_{o in this half} A1[ik,p,o]*U[o][q]; 16-lane butterfly
    float2 S[4][5];
    #pragma unroll
    for(int p=0;p<4;p++)
        #pragma unroll
        for(int q=0;q<5;q++) S[p][q] = make_float2(0.f,0.f);
    #pragma unroll
    for(int oi=0;oi<4;oi++){
        int o = oh*64 + ol + 16*oi;
        const float2* a1 = A1T + (size_t)o*IKP + (size_t)ik*M1;
        float2 a1v[4];
        #pragma unroll
        for(int p=0;p<4;p++) a1v[p] = a1[p];
        #pragma unroll
        for(int p=0;p<4;p++)
            #pragma unroll
            for(int q=0;q<5;q++) S[p][q] = cmadd(S[p][q], a1v[p], U[oi][q]);
    }
    #pragma unroll
    for(int m=1;m<16;m<<=1){
        #pragma unroll
        for(int p=0;p<4;p++)
            #pragma unroll
            for(int q=0;q<5;q++){
                S[p][q].x += __shfl_xor(S[p][q].x, m);
                S[p][q].y += __shfl_xor(S[p][q].y, m);
            }
    }
    if(ol==0){
        float2* dst = part + ((size_t)((b*CO + kl)*CI + i)*2 + oh)*(M1*M2);
        #pragma unroll
        for(int p=0;p<4;p++)
            #pragma unroll
            for(int q=0;q<5;q++) dst[p*5+q] = S[p][q];
    }
}

// res2[bk][pq] = sum_i w[i*CO+k][pq] * (part[(bk*CI+i)*2+0][pq] + part[(bk*CI+i)*2+1][pq])
// 256 blocks (bk) x 128 thr (i = t&31, g = t>>5 covers 5 pq); shuffle-reduce over i.
__global__ void k_res2_red(const float2* part, const float* wrr, const float* wri, float2* res2){
    int bk = blockIdx.x;
    int t = threadIdx.x;
    int i = t & 31, g = t >> 5;
    int k = bk & (CO-1);
    int ikk = i*CO + k;
    float2 acc[5];
    #pragma unroll
    for(int e=0;e<5;e++){
        int pq = g*5 + e;
        float2 w = make_float2(wrr[ikk*(M1*M2)+pq], wri[ikk*(M1*M2)+pq]);
        const float2* pp = part + ((size_t)(bk*CI + i)*2)*(M1*M2) + pq;
        float2 s0 = pp[0], s1 = pp[M1*M2];
        float2 s = make_float2(s0.x+s1.x, s0.y+s1.y);
        acc[e] = cmul(w, s);
    }
    #pragma unroll
    for(int m=1;m<32;m<<=1){
        #pragma unroll
        for(int e=0;e<5;e++){
            acc[e].x += __shfl_xor(acc[e].x, m);
            acc[e].y += __shfl_xor(acc[e].y, m);
        }
    }
    if(i==0){
        #pragma unroll
        for(int e=0;e<5;e++) res2[(size_t)bk*(M1*M2) + g*5 + e] = acc[e];
    }
}

// x2[b,j,y,x] += (1/N^2) * Re( sum_{c,p,q} res2[b,c,p,q]*E1[c,j,p,y]*E2[c,j,q,x] )
// grid = (b, j, yh): 512 blocks (2/CU); 256 thr = 16 yt x 16 xt; thread tile 4y x 8x.
__global__ void __launch_bounds__(256) k_x2(const float2* res2, const float2* E1,
                                            const float2* E2, float* out){
    __shared__ __align__(16) float2 res2s[CI*M1*M2];        // 640
    __shared__ __align__(16) float2 Wt[M1*N];               // 512
    __shared__ __align__(16) float2 buf[2][M1*64 + M2*N];   // 896 each: E1s[0,256) + E2s[256,896)
    int t = threadIdx.x;
    int yh = blockIdx.x & 1;
    int j  = (blockIdx.x >> 1) & (CO-1);
    int b  = blockIdx.x >> 6;
    int xt = t & 15, yt = t >> 4;

    // stage res2 for this b: 640 float2 = 320 float4, contiguous
    {
        const float4* s4 = (const float4*)(res2 + (size_t)b*CO*M1*M2);
        float4* d4 = (float4*)res2s;
        d4[t] = s4[t];
        if(t < 64) d4[256+t] = s4[256+t];
    }

    // staging slots: slot0 = e=t (E1 if t<128 else E2), slot1 = e=t+256 (E2, t<192)
    const bool is1_0 = (t < 128);
    const bool ok1 = (t < 192);
    int off0, dst0;
    if(is1_0){ int pp = t >> 5, rem = (t & 31) << 1; off0 = pp*N + rem; dst0 = pp*64 + rem; }
    else     { int g = t - 128; int qq = g >> 6, xi = (g & 63) << 1; off0 = qq*N + xi; dst0 = 256 + qq*128 + xi; }
    int g1 = t + 128; int qq1 = g1 >> 6, xi1 = (g1 & 63) << 1;
    int off1 = qq1*N + xi1;
    int dst1 = 256 + qq1*128 + xi1;

    const float2* E1c = E1 + ((size_t)j*M1)*N + yh*64;   // advances by CO*M1*N per c
    const float2* E2c = E2 + ((size_t)j*M2)*N;           // advances by CO*M2*N per c

    // preload c=0 and commit to buf[0]
    float4 pre0 = *(const float4*)((is1_0 ? E1c : E2c) + off0);
    float4 pre1 = ok1 ? *(const float4*)(E2c + off1) : make_float4(0.f,0.f,0.f,0.f);
    *(float4*)(&buf[0][dst0]) = pre0;
    if(ok1) *(float4*)(&buf[0][dst1]) = pre1;
    int cur = 0;
    __syncthreads();

    float acc[4][8];
    #pragma unroll
    for(int yy=0;yy<4;yy++)
        #pragma unroll
        for(int s=0;s<8;s++) acc[yy][s] = 0.f;

    for(int c=0; c<CI; c++){
        // ---- Wt compute: 512 elems, 2/thread, from E2s[cur] + res2s ----
        const float2* E2s = buf[cur] + 256;
        #pragma unroll
        for(int s=0;s<2;s++){
            int e = t + 256*s;
            int pp = e >> 7, xi = e & 127;
            const float2* rr = res2s + c*(M1*M2) + pp*M2;
            float2 w = make_float2(0.f,0.f);
            #pragma unroll
            for(int q=0;q<M2;q++) w = cmadd(w, rr[q], E2s[q*128 + xi]);
            Wt[pp*128 + xi] = w;
        }
        // ---- issue prefetch of c+1 (consumed after compute) ----
        if(c+1 < CI){
            E1c += (size_t)CO*M1*N;
            E2c += (size_t)CO*M2*N;
            pre0 = *(const float4*)((is1_0 ? E1c : E2c) + off0);
            if(ok1) pre1 = *(const float4*)(E2c + off1);
        }
        __syncthreads();   // Wt visible; E2s[cur] reads done

        // ---- acc compute: 4y x 8x tile ----
        const float2* E1s = buf[cur];
        #pragma unroll
        for(int p=0;p<4;p++){
            float2 e1[4];
            float4 a  = *(const float4*)(E1s + p*64 + yt*4);
            float4 bq = *(const float4*)(E1s + p*64 + yt*4 + 2);
            e1[0]=make_float2(a.x,a.y);  e1[1]=make_float2(a.z,a.w);
            e1[2]=make_float2(bq.x,bq.y); e1[3]=make_float2(bq.z,bq.w);
            #pragma unroll
            for(int s=0;s<4;s++){
                float4 wv = *(const float4*)(Wt + p*128 + 32*s + 2*xt);
                #pragma unroll
                for(int yy=0;yy<4;yy++){
                    float2 e = e1[yy];
                    acc[yy][2*s]   = fmaf(e.x, wv.x, fmaf(-e.y, wv.y, acc[yy][2*s]));
                    acc[yy][2*s+1] = fmaf(e.x, wv.z, fmaf(-e.y, wv.w, acc[yy][2*s+1]));
                }
            }
        }
        // ---- commit prefetched tile to the other buffer ----
        if(c+1 < CI){
            float2* nb = buf[cur^1];
            *(float4*)(nb + dst0) = pre0;
            if(ok1) *(float4*)(nb + dst1) = pre1;
        }
        cur ^= 1;
        __syncthreads();   // next-buf writes visible; Wt reads done before next overwrite
    }

    const float sc = 1.0f/((float)N*(float)N);
    size_t base = (size_t)(b*CO + j)*(N*N) + (size_t)yh*64*N;
    #pragma unroll
    for(int yy=0;yy<4;yy++){
        float* orow = out + base + (size_t)(yt*4 + yy)*N;
        #pragma unroll
        for(int s=0;s<4;s++){
            float2* dst = (float2*)(orow + 32*s + 2*xt);
            float2 old = *dst;
            *dst = make_float2(old.x + acc[yy][2*s]*sc, old.y + acc[yy][2*s+1]*sc);
        }
    }
}

extern "C" void kernel_launch(void* const* d_in, const int* in_sizes, int n_in,
                              void* d_out, int out_size, void* d_ws, size_t ws_size,
                              hipStream_t stream){
    const float* x    = (const float*)d_in[0];
    const float* wp1r = (const float*)d_in[1];
    const float* wp1i = (const float*)d_in[2];
    const float* wp2r = (const float*)d_in[3];
    const float* wp2i = (const float*)d_in[4];
    const float* wrr  = (const float*)d_in[5];
    const float* wri  = (const float*)d_in[6];
    const float* ty   = (const float*)d_in[7];
    const float* tx   = (const float*)d_in[8];
    float* out = (float*)d_out;
    float2* ws = (float2*)d_ws;

    const size_t NCIMG = (size_t)B*CI*N*N;        // 4194304 complexes
    float2* bufA  = ws;
    float2* alpha = bufA  + NCIMG;
    float2* res1  = alpha + NCIMG;
    float2* A1T   = res1  + NCIMG;                // N*IKP
    float2* A2    = A1T   + (size_t)N*IKP;        // IKQ*N
    float2* W2N   = A2    + (size_t)IKQ*N;        // IKP*N (natural layout [ikp][x])
    float2* E1    = W2N   + (size_t)N*IKP;        // IKP*N
    float2* E2    = E1    + (size_t)IKP*N;        // IKQ*N
    float2* res2  = E2    + (size_t)IKQ*N;        // B*CO*M1*M2
    float2* part  = res2  + (size_t)B*CO*M1*M2;   // B*CO*CI*2*M1*M2 = 327680

    k_A1T<<<(N*IKP)/256, 256, 0, stream>>>(wp1r, wp1i, ty, A1T);
    k_E  <<<(IKP*N)/256, 256, 0, stream>>>(wp1r, wp1i, ty, E1);
    k_A2 <<<(IKQ*N)/256, 256, 0, stream>>>(wp2r, wp2i, tx, A2);
    k_E  <<<(IKQ*N)/256, 256, 0, stream>>>(wp2r, wp2i, tx, E2);
    k_W2N<<<(IKP*N)/256, 256, 0, stream>>>(wrr, wri, A2, W2N);

    // forward fft2: rows (real in) then cols
    k_fft_rows<0,1,0><<<(B*CI*N)/16, 256, 0, stream>>>((const void*)x, bufA);
    k_fft_cols<0,0,0><<<B*CI*8, 256, 0, stream>>>(bufA, alpha, nullptr);

    k_res1<<<N*8, 256, 0, stream>>>(alpha, A1T, W2N, res1);
    k_S_res2<<<B*CI*2, 512, 0, stream>>>(alpha, A2, A1T, part);
    k_res2_red<<<B*CO, 128, 0, stream>>>(part, wrr, wri, res2);

    // inverse fft2: rows (1/N) then cols (real out, 1/N)
    k_fft_rows<1,0,1><<<(B*CO*N)/16, 256, 0, stream>>>((const void*)res1, bufA);
    k_fft_cols<1,1,1><<<B*CO*8, 256, 0, stream>>>(bufA, nullptr, out);
    k_x2<<<B*CO*2, 256, 0, stream>>>(res2, E1, E2, out);
}

// Round 11
// 309.805 us; speedup vs baseline: 1.0413x; 1.0018x over previous
//
#include <hip/hip_runtime.h>
#include <math.h>

#define N 128
#define B 8
#define CI 32
#define CO 32
#define M1 4
#define M2 5
#define IK (CI*CO)       // 1024
#define IKP (IK*M1)      // 4096
#define IKQ (IK*M2)      // 5120
#define TWO_PI_F 6.2831853071795864769f

// 4 v_fma per cmadd, guaranteed
__device__ __forceinline__ float2 cmul(float2 a, float2 b){
    return make_float2(fmaf(a.x,b.x,-(a.y*b.y)), fmaf(a.x,b.y,a.y*b.x));
}
__device__ __forceinline__ float2 cmadd(float2 acc, float2 a, float2 b){
    acc.x = fmaf(a.x, b.x, fmaf(-a.y, b.y, acc.x));
    acc.y = fmaf(a.x, b.y, fmaf( a.y, b.x, acc.y));
    return acc;
}

// A1T[o][ik*M1+p] = 1/(i*2pi*f(o) - wp1[ik,p]); freq-major for contiguous per-o slices
__global__ void k_A1T(const float* wr_, const float* wi_, const float* t_, float2* A1T){
    int idx = blockIdx.x*256 + threadIdx.x;      // [0, N*IKP)
    int o   = idx >> 12;                          // /IKP
    int ikp = idx & (IKP-1);
    float d = t_[1]-t_[0];
    float invnd = 1.0f/((float)N*d);
    int kk = (o < N/2) ? o : o - N;
    float lam = TWO_PI_F * (float)kk * invnd;
    float dr = -wr_[ikp];
    float di = lam - wi_[ikp];
    float inv = 1.0f/(dr*dr + di*di);
    A1T[idx] = make_float2(dr*inv, -di*inv);
}

// A2[ikq][x] natural layout
__global__ void k_A2(const float* wr_, const float* wi_, const float* t_, float2* A2){
    int idx = blockIdx.x*256 + threadIdx.x;      // [0, IKQ*N)
    int ikq = idx >> 7; int xx = idx & (N-1);
    float d = t_[1]-t_[0];
    float invnd = 1.0f/((float)N*d);
    int kk = (xx < N/2) ? xx : xx - N;
    float lam = TWO_PI_F * (float)kk * invnd;
    float dr = -wr_[ikq];
    float di = lam - wi_[ikq];
    float inv = 1.0f/(dr*dr + di*di);
    A2[idx] = make_float2(dr*inv, -di*inv);
}

// E[ikp][y] = exp(wp[ikp] * t[y])
__global__ void k_E(const float* wr_, const float* wi_, const float* t_, float2* E){
    int idx = blockIdx.x*256 + threadIdx.x;
    int ikp = idx >> 7; int y = idx & (N-1);
    float t = t_[y];
    float m = expf(wr_[ikp]*t);
    float s, c; sincosf(wi_[ikp]*t, &s, &c);
    E[idx] = make_float2(m*c, m*s);
}

// W2N[ikp][x] = sum_q wr[ik,p,q] * A2[ik,q,x]   (natural layout; coalesced store)
__global__ void k_W2N(const float* wrr, const float* wri, const float2* A2, float2* W2N){
    int idx = blockIdx.x*256 + threadIdx.x;      // [0, IKP*N)
    int ikp = idx >> 7; int xx = idx & (N-1);
    int ik = ikp >> 2; int p = ikp & 3;
    float2 acc = make_float2(0.f,0.f);
    const float* wr0 = wrr + ik*(M1*M2) + p*M2;
    const float* wi0 = wri + ik*(M1*M2) + p*M2;
    const float2* a2 = A2 + (size_t)ik*(M2*N) + xx;
    #pragma unroll
    for(int q=0;q<M2;q++){
        float2 w = make_float2(wr0[q], wi0[q]);
        acc = cmadd(acc, w, a2[q*N]);
    }
    W2N[(size_t)ikp*N + xx] = acc;
}

// ---------- four-step FFT, 128 = 16 x 8 ----------
// Twiddle table: twc/tws[j] = sincos(sgn*2pi*j/128). Arguments for t16 (j*8) and t8
// (j*16) are bit-identical to the original sincosf calls (exact pow2 scaling).
// Replaces 32 sincosf/thread (~1600 VALU cyc) with 0.5 sincosf/thread + LDS loads.
template<int SIGNPOS, int REALIN, int SCALE>
__global__ void __launch_bounds__(256) k_fft_rows(const void* in_, float2* out){
    const float sgn = SIGNPOS ? 1.0f : -1.0f;
    __shared__ float tre[16*132];
    __shared__ float tim_[16*132];
    __shared__ float zre[16*136];
    __shared__ float zim[16*136];
    __shared__ float twc[128], tws[128];
    int t = threadIdx.x;
    size_t row0 = (size_t)blockIdx.x * 16;

    if(t < 128){ float s,c; sincosf(sgn*(TWO_PI_F/128.f)*(float)t, &s,&c); twc[t]=c; tws[t]=s; }

    if(REALIN){
        const float* src = (const float*)in_ + row0*N;
        #pragma unroll
        for(int j=0;j<8;j++){
            int idx = t + 256*j; int r = idx>>7, cl = idx&127;
            tre[r*132+cl] = src[idx];
        }
    } else {
        const float2* src = (const float2*)in_ + row0*N;
        #pragma unroll
        for(int j=0;j<8;j++){
            int idx = t + 256*j; int r = idx>>7, cl = idx&127;
            float2 v = src[idx];
            tre[r*132+cl] = v.x; tim_[r*132+cl] = v.y;
        }
    }
    __syncthreads();

    float t16c[16], t16s[16];
    #pragma unroll
    for(int j=0;j<16;j++){ t16c[j]=twc[8*j]; t16s[j]=tws[8*j]; }

    int r = t>>4, u = t&15, b = u&7, h = u>>3;
    float xr[16], xi[16];
    #pragma unroll
    for(int a=0;a<16;a++){
        float vr = tre[r*132 + 8*a + b];
        float vi = REALIN ? 0.f : tim_[r*132 + 8*a + b];
        if(h && (a&1)){ vr = -vr; vi = -vi; }
        xr[a]=vr; xi[a]=vi;
    }
    #pragma unroll
    for(int cc=0; cc<8; cc++){
        float yr=0.f, yi=0.f;
        #pragma unroll
        for(int a=0;a<16;a++){
            int j = (a*cc)&15;
            if(REALIN){
                yr = fmaf(xr[a], t16c[j], yr);
                yi = fmaf(xr[a], t16s[j], yi);
            } else {
                yr = fmaf(xr[a], t16c[j], yr); yr = fmaf(-xi[a], t16s[j], yr);
                yi = fmaf(xr[a], t16s[j], yi); yi = fmaf( xi[a], t16c[j], yi);
            }
        }
        int c = 8*h + cc;
        int jw = b*c;                 // < 128
        float co = twc[jw], s = tws[jw];
        zre[r*136 + b*17 + c] = fmaf(yr,co,-(yi*s));
        zim[r*136 + b*17 + c] = fmaf(yr,s,  yi*co);
    }
    __syncthreads();

    float t8c[8], t8s[8];
    #pragma unroll
    for(int j=0;j<8;j++){ t8c[j]=twc[16*j]; t8s[j]=tws[16*j]; }
    int r2 = t>>4, c2 = t&15;
    float zr_[8], zi_[8];
    #pragma unroll
    for(int bb=0;bb<8;bb++){ zr_[bb]=zre[r2*136 + bb*17 + c2]; zi_[bb]=zim[r2*136 + bb*17 + c2]; }
    float2* dst = out + (row0 + r2)*N;
    #pragma unroll
    for(int d=0; d<8; d++){
        float Xr=0.f, Xi=0.f;
        #pragma unroll
        for(int bb=0;bb<8;bb++){
            int j=(bb*d)&7;
            Xr = fmaf(zr_[bb], t8c[j], Xr); Xr = fmaf(-zi_[bb], t8s[j], Xr);
            Xi = fmaf(zr_[bb], t8s[j], Xi); Xi = fmaf( zi_[bb], t8c[j], Xi);
        }
        if(SCALE){ Xr *= (1.f/128.f); Xi *= (1.f/128.f); }
        dst[c2 + 16*d] = make_float2(Xr, Xi);
    }
}

template<int SIGNPOS, int REALOUT, int SCALE>
__global__ void __launch_bounds__(256) k_fft_cols(const float2* in, float2* outc, float* outr){
    const float sgn = SIGNPOS ? 1.0f : -1.0f;
    __shared__ float tre[N*17];
    __shared__ float tim_[N*17];
    __shared__ float zre[8*16*17];
    __shared__ float zim[8*16*17];
    __shared__ float twc[128], tws[128];
    int t = threadIdx.x;
    int img = blockIdx.x >> 3; int x0 = (blockIdx.x & 7)*16;

    if(t < 128){ float s,c; sincosf(sgn*(TWO_PI_F/128.f)*(float)t, &s,&c); twc[t]=c; tws[t]=s; }

    const float2* src = in + (size_t)img*N*N + x0;
    #pragma unroll
    for(int j=0;j<8;j++){
        int idx = t + 256*j; int y = idx>>4, xc = idx&15;
        float2 v = src[y*N + xc];
        tre[y*17+xc]=v.x; tim_[y*17+xc]=v.y;
    }
    __syncthreads();

    float t16c[16], t16s[16];
    #pragma unroll
    for(int j=0;j<16;j++){ t16c[j]=twc[8*j]; t16s[j]=tws[8*j]; }

    int xc = t&15, u = t>>4, b = u&7, h = u>>3;
    float xr[16], xi[16];
    #pragma unroll
    for(int a=0;a<16;a++){
        int y = 8*a + b;
        float vr = tre[y*17+xc];
        float vi = tim_[y*17+xc];
        if(h && (a&1)){ vr = -vr; vi = -vi; }
        xr[a]=vr; xi[a]=vi;
    }
    #pragma unroll
    for(int cc=0; cc<8; cc++){
        float yr=0.f, yi=0.f;
        #pragma unroll
        for(int a=0;a<16;a++){
            int j = (a*cc)&15;
            yr = fmaf(xr[a], t16c[j], yr); yr = fmaf(-xi[a], t16s[j], yr);
            yi = fmaf(xr[a], t16s[j], yi); yi = fmaf( xi[a], t16c[j], yi);
        }
        int c = 8*h + cc;
        int jw = b*c;                 // < 128
        float co = twc[jw], s = tws[jw];
        zre[(b*16 + c)*17 + xc] = fmaf(yr,co,-(yi*s));
        zim[(b*16 + c)*17 + xc] = fmaf(yr,s,  yi*co);
    }
    __syncthreads();

    float t8c[8], t8s[8];
    #pragma unroll
    for(int j=0;j<8;j++){ t8c[j]=twc[16*j]; t8s[j]=tws[16*j]; }
    int c2 = t>>4; int x2 = t&15;
    float zr_[8], zi_[8];
    #pragma unroll
    for(int bb=0;bb<8;bb++){ zr_[bb]=zre[(bb*16 + c2)*17 + x2]; zi_[bb]=zim[(bb*16 + c2)*17 + x2]; }
    #pragma unroll
    for(int d=0; d<8; d++){
        float Xr=0.f, Xi=0.f;
        #pragma unroll
        for(int bb=0;bb<8;bb++){
            int j=(bb*d)&7;
            Xr = fmaf(zr_[bb], t8c[j], Xr); Xr = fmaf(-zi_[bb], t8s[j], Xr);
            Xi = fmaf(zr_[bb], t8s[j], Xi); Xi = fmaf( zi_[bb], t8c[j], Xi);
        }
        int ky = c2 + 16*d;
        if(REALOUT){
            outr[(size_t)img*N*N + ky*N + x0 + x2] = Xr * (SCALE ? (1.f/128.f) : 1.f);
        } else {
            if(SCALE){ Xr *= (1.f/128.f); Xi *= (1.f/128.f); }
            outc[(size_t)img*N*N + ky*N + x0 + x2] = make_float2(Xr, Xi);
        }
    }
}

// res1[b,k,o,x] = sum_i alpha[b,i,o,x] * sum_p A1T[o][ik,p] * W2N[ik,p][x]
__global__ void __launch_bounds__(256) k_res1(const float2* alpha, const float2* A1T,
                                              const float2* W2N, float2* res1){
    __shared__ float4 At4[B*CI*8];   // [img][xq] , xq = x-pair; 32 KB
    int t = threadIdx.x;
    int o  = blockIdx.x >> 3;
    int x0 = (blockIdx.x & 7) * 16;

    {
        int im0 = t >> 3, xq = t & 7;
        #pragma unroll
        for(int j=0;j<8;j++){
            int im = im0 + 32*j;
            At4[im*8 + xq] = *(const float4*)(alpha + (size_t)im*(N*N) + o*N + x0 + 2*xq);
        }
    }
    __syncthreads();

    int k = t >> 3, xh = t & 7;
    float2 acc[B][2];
    #pragma unroll
    for(int b=0;b<B;b++){ acc[b][0]=make_float2(0.f,0.f); acc[b][1]=make_float2(0.f,0.f); }

    const float2* a1base = A1T + (size_t)o*IKP + k*M1;            // + i*128
    const float2* w2base = W2N + ((size_t)k*M1)*N + x0 + 2*xh;    // + i*128*N + p*N

    #pragma unroll 2
    for(int i=0;i<CI;i++){
        float4 a1a = *(const float4*)(a1base + (size_t)i*128);
        float4 a1b = *(const float4*)(a1base + (size_t)i*128 + 2);
        float2 a1v[M1] = { make_float2(a1a.x,a1a.y), make_float2(a1a.z,a1a.w),
                           make_float2(a1b.x,a1b.y), make_float2(a1b.z,a1b.w) };
        float2 h0 = make_float2(0.f,0.f), h1 = make_float2(0.f,0.f);
        const float2* w2 = w2base + (size_t)i*(128*N);
        #pragma unroll
        for(int p=0;p<M1;p++){
            float4 wv = *(const float4*)(w2 + (size_t)p*N);
            h0 = cmadd(h0, a1v[p], make_float2(wv.x,wv.y));
            h1 = cmadd(h1, a1v[p], make_float2(wv.z,wv.w));
        }
        #pragma unroll
        for(int b=0;b<B;b++){
            float4 av = At4[(b*CI + i)*8 + xh];
            acc[b][0] = cmadd(acc[b][0], make_float2(av.x,av.y), h0);
            acc[b][1] = cmadd(acc[b][1], make_float2(av.z,av.w), h1);
        }
    }

    #pragma unroll
    for(int b=0;b<B;b++){
        float4 v = make_float4(acc[b][0].x, acc[b][0].y, acc[b][1].x, acc[b][1].y);
        *(float4*)(res1 + (size_t)(b*CO + k)*(N*N) + o*N + x0 + 2*xh) = v;
    }
}

// per (b, i, oh): grid 512 x 512 thr — round-9 proven version (78us, VGPR 60, no spill).
__global__ void __launch_bounds__(512, 4) k_S_res2(const float2* alpha, const float2* A2,
                                                   const float2* A1T, float2* part){
    __shared__ float2 tile[64*33];    // [o-row][xc<32], pad 33
    __shared__ float2 A2c[160*33];    // [row = kk*5+q][xc], pad 33
    int t = threadIdx.x;
    int ol = t & 15;
    int kl = t >> 4;                  // 0..31 = k
    int bid = blockIdx.x;             // (b*CI + i)*2 + oh
    int oh = bid & 1;
    int i  = (bid >> 1) & (CI-1);
    int b  = bid >> 6;
    int ik = i*CO + kl;
    const float2* asrc = alpha + ((size_t)(b*CI + i))*(N*N) + (size_t)oh*64*N;
    const float2* a2base = A2 + (size_t)i*(CO*M2*N);   // row r -> + r*N

    const int txc = t & 31, trow = t >> 5;   // alpha: rows trow+16j (j<4)
    float2 U[4][5];                           // [oi][q]
    #pragma unroll
    for(int oi=0;oi<4;oi++)
        #pragma unroll
        for(int q=0;q<5;q++) U[oi][q] = make_float2(0.f,0.f);

    float2 pre[4];
    #pragma unroll
    for(int j=0;j<4;j++) pre[j] = asrc[(trow + 16*j)*N + txc];

    for(int c=0; c<4; c++){
        __syncthreads();   // previous chunk's compute done
        #pragma unroll
        for(int j=0;j<4;j++) tile[(trow + 16*j)*33 + txc] = pre[j];
        #pragma unroll
        for(int s=0;s<10;s++){
            int rs = s*16 + trow;             // 0..159
            A2c[rs*33 + txc] = a2base[(size_t)rs*N + c*32 + txc];
        }
        if(c < 3){
            #pragma unroll
            for(int j=0;j<4;j++) pre[j] = asrc[(trow + 16*j)*N + (c+1)*32 + txc];
        }
        __syncthreads();
        #pragma unroll 4
        for(int xc=0; xc<32; xc++){
            float2 a2v[5];
            const float2* a2row = A2c + (kl*5)*33 + xc;
            #pragma unroll
            for(int q=0;q<5;q++) a2v[q] = a2row[q*33];
            #pragma unroll
            for(int oi=0;oi<4;oi++){
                float2 av = tile[(ol + 16*oi)*33 + xc];
                #pragma unroll
                for(int q=0;q<5;q++) U[oi][q] = cmadd(U[oi][q], av, a2v[q]);
            }
        }
    }

    // S-phase: S[p][q] = sum_{o in this half} A1[ik,p,o]*U[o][q]; 16-lane butterfly
    float2 S[4][5];
    #pragma unroll
    for(int p=0;p<4;p++)
        #pragma unroll
        for(int q=0;q<5;q++) S[p][q] = make_float2(0.f,0.f);
    #pragma unroll
    for(int oi=0;oi<4;oi++){
        int o = oh*64 + ol + 16*oi;
        const float2* a1 = A1T + (size_t)o*IKP + (size_t)ik*M1;
        float2 a1v[4];
        #pragma unroll
        for(int p=0;p<4;p++) a1v[p] = a1[p];
        #pragma unroll
        for(int p=0;p<4;p++)
            #pragma unroll
            for(int q=0;q<5;q++) S[p][q] = cmadd(S[p][q], a1v[p], U[oi][q]);
    }
    #pragma unroll
    for(int m=1;m<16;m<<=1){
        #pragma unroll
        for(int p=0;p<4;p++)
            #pragma unroll
            for(int q=0;q<5;q++){
                S[p][q].x += __shfl_xor(S[p][q].x, m);
                S[p][q].y += __shfl_xor(S[p][q].y, m);
            }
    }
    if(ol==0){
        float2* dst = part + ((size_t)((b*CO + kl)*CI + i)*2 + oh)*(M1*M2);
        #pragma unroll
        for(int p=0;p<4;p++)
            #pragma unroll
            for(int q=0;q<5;q++) dst[p*5+q] = S[p][q];
    }
}

// res2[bk][pq] = sum_i w[i*CO+k][pq] * (part[(bk*CI+i)*2+0][pq] + part[(bk*CI+i)*2+1][pq])
__global__ void k_res2_red(const float2* part, const float* wrr, const float* wri, float2* res2){
    int bk = blockIdx.x;
    int t = threadIdx.x;
    int i = t & 31, g = t >> 5;
    int k = bk & (CO-1);
    int ikk = i*CO + k;
    float2 acc[5];
    #pragma unroll
    for(int e=0;e<5;e++){
        int pq = g*5 + e;
        float2 w = make_float2(wrr[ikk*(M1*M2)+pq], wri[ikk*(M1*M2)+pq]);
        const float2* pp = part + ((size_t)(bk*CI + i)*2)*(M1*M2) + pq;
        float2 s0 = pp[0], s1 = pp[M1*M2];
        float2 s = make_float2(s0.x+s1.x, s0.y+s1.y);
        acc[e] = cmul(w, s);
    }
    #pragma unroll
    for(int m=1;m<32;m<<=1){
        #pragma unroll
        for(int e=0;e<5;e++){
            acc[e].x += __shfl_xor(acc[e].x, m);
            acc[e].y += __shfl_xor(acc[e].y, m);
        }
    }
    if(i==0){
        #pragma unroll
        for(int e=0;e<5;e++) res2[(size_t)bk*(M1*M2) + g*5 + e] = acc[e];
    }
}

// x2[b,j,y,x] += (1/N^2) * Re( sum_{c,p,q} res2[b,c,p,q]*E1[c,j,p,y]*E2[c,j,q,x] )
// grid = (b, j, yq): 1024 blocks = 4/CU = 4 waves/SIMD (was 2/SIMD at yh-split).
// 256 thr = 16 yt x 16 xt; thread tile 2y x 8x. Wt recomputed per quarter (~15% VALU).
__global__ void __launch_bounds__(256) k_x2(const float2* res2, const float2* E1,
                                            const float2* E2, float* out){
    __shared__ __align__(16) float2 res2s[CI*M1*M2];        // 640
    __shared__ __align__(16) float2 Wt[M1*N];               // 512
    __shared__ __align__(16) float2 buf[2][M1*32 + M2*N];   // 768 each: E1s[0,128) + E2s[128,768)
    int t = threadIdx.x;
    int yq = blockIdx.x & 3;
    int j  = (blockIdx.x >> 2) & (CO-1);
    int b  = blockIdx.x >> 7;
    int xt = t & 15, yt = t >> 4;

    // stage res2 for this b: 640 float2 = 320 float4, contiguous
    {
        const float4* s4 = (const float4*)(res2 + (size_t)b*CO*M1*M2);
        float4* d4 = (float4*)res2s;
        d4[t] = s4[t];
        if(t < 64) d4[256+t] = s4[256+t];
    }

    // buf = 768 f2 = 384 f4 per buffer. slot0: e=t (t<64 -> E1, t in [64,256) -> E2 g=t-64);
    // slot1: t<128 -> E2 g=t+192.
    const bool is1_0 = (t < 64);
    const bool ok1 = (t < 128);
    int off0, dst0;
    if(is1_0){ int pp = t >> 4, rem = (t & 15) << 1; off0 = pp*N + rem; dst0 = pp*32 + rem; }
    else     { int g = t - 64; int qq = g >> 6, xi = (g & 63) << 1; off0 = qq*N + xi; dst0 = 128 + qq*128 + xi; }
    int g1 = t + 192; int qq1 = g1 >> 6, xi1 = (g1 & 63) << 1;
    int off1 = qq1*N + xi1;
    int dst1 = 128 + qq1*128 + xi1;

    const float2* E1c = E1 + ((size_t)j*M1)*N + yq*32;   // advances by CO*M1*N per c
    const float2* E2c = E2 + ((size_t)j*M2)*N;           // advances by CO*M2*N per c

    // preload c=0 and commit to buf[0]
    float4 pre0 = *(const float4*)((is1_0 ? E1c : E2c) + off0);
    float4 pre1 = ok1 ? *(const float4*)(E2c + off1) : make_float4(0.f,0.f,0.f,0.f);
    *(float4*)(&buf[0][dst0]) = pre0;
    if(ok1) *(float4*)(&buf[0][dst1]) = pre1;
    int cur = 0;
    __syncthreads();

    float acc[2][8];
    #pragma unroll
    for(int yy=0;yy<2;yy++)
        #pragma unroll
        for(int s=0;s<8;s++) acc[yy][s] = 0.f;

    for(int c=0; c<CI; c++){
        // ---- Wt compute: 512 elems, 2/thread, from E2s[cur] + res2s ----
        const float2* E2s = buf[cur] + 128;
        #pragma unroll
        for(int s=0;s<2;s++){
            int e = t + 256*s;
            int pp = e >> 7, xi = e & 127;
            const float2* rr = res2s + c*(M1*M2) + pp*M2;
            float2 w = make_float2(0.f,0.f);
            #pragma unroll
            for(int q=0;q<M2;q++) w = cmadd(w, rr[q], E2s[q*128 + xi]);
            Wt[pp*128 + xi] = w;
        }
        // ---- issue prefetch of c+1 (consumed after compute) ----
        if(c+1 < CI){
            E1c += (size_t)CO*M1*N;
            E2c += (size_t)CO*M2*N;
            pre0 = *(const float4*)((is1_0 ? E1c : E2c) + off0);
            if(ok1) pre1 = *(const float4*)(E2c + off1);
        }
        __syncthreads();   // Wt visible; E2s[cur] reads done

        // ---- acc compute: 2y x 8x tile ----
        const float2* E1s = buf[cur];
        #pragma unroll
        for(int p=0;p<4;p++){
            float4 a = *(const float4*)(E1s + p*32 + yt*2);
            float2 e0 = make_float2(a.x,a.y);
            float2 e1v = make_float2(a.z,a.w);
            #pragma unroll
            for(int s=0;s<4;s++){
                float4 wv = *(const float4*)(Wt + p*128 + 32*s + 2*xt);
                acc[0][2*s]   = fmaf(e0.x, wv.x, fmaf(-e0.y, wv.y, acc[0][2*s]));
                acc[0][2*s+1] = fmaf(e0.x, wv.z, fmaf(-e0.y, wv.w, acc[0][2*s+1]));
                acc[1][2*s]   = fmaf(e1v.x, wv.x, fmaf(-e1v.y, wv.y, acc[1][2*s]));
                acc[1][2*s+1] = fmaf(e1v.x, wv.z, fmaf(-e1v.y, wv.w, acc[1][2*s+1]));
            }
        }
        // ---- commit prefetched tile to the other buffer ----
        if(c+1 < CI){
            float2* nb = buf[cur^1];
            *(float4*)(nb + dst0) = pre0;
            if(ok1) *(float4*)(nb + dst1) = pre1;
        }
        cur ^= 1;
        __syncthreads();   // next-buf writes visible; Wt reads done before next overwrite
    }

    const float sc = 1.0f/((float)N*(float)N);
    size_t base = (size_t)(b*CO + j)*(N*N) + (size_t)(yq*32)*N;
    #pragma unroll
    for(int yy=0;yy<2;yy++){
        float* orow = out + base + (size_t)(yt*2 + yy)*N;
        #pragma unroll
        for(int s=0;s<4;s++){
            float2* dst = (float2*)(orow + 32*s + 2*xt);
            float2 old = *dst;
            *dst = make_float2(old.x + acc[yy][2*s]*sc, old.y + acc[yy][2*s+1]*sc);
        }
    }
}

extern "C" void kernel_launch(void* const* d_in, const int* in_sizes, int n_in,
                              void* d_out, int out_size, void* d_ws, size_t ws_size,
                              hipStream_t stream){
    const float* x    = (const float*)d_in[0];
    const float* wp1r = (const float*)d_in[1];
    const float* wp1i = (const float*)d_in[2];
    const float* wp2r = (const float*)d_in[3];
    const float* wp2i = (const float*)d_in[4];
    const float* wrr  = (const float*)d_in[5];
    const float* wri  = (const float*)d_in[6];
    const float* ty   = (const float*)d_in[7];
    const float* tx   = (const float*)d_in[8];
    float* out = (float*)d_out;
    float2* ws = (float2*)d_ws;

    const size_t NCIMG = (size_t)B*CI*N*N;        // 4194304 complexes
    float2* bufA  = ws;
    float2* alpha = bufA  + NCIMG;
    float2* res1  = alpha + NCIMG;
    float2* A1T   = res1  + NCIMG;                // N*IKP
    float2* A2    = A1T   + (size_t)N*IKP;        // IKQ*N
    float2* W2N   = A2    + (size_t)IKQ*N;        // IKP*N (natural layout [ikp][x])
    float2* E1    = W2N   + (size_t)N*IKP;        // IKP*N
    float2* E2    = E1    + (size_t)IKP*N;        // IKQ*N
    float2* res2  = E2    + (size_t)IKQ*N;        // B*CO*M1*M2
    float2* part  = res2  + (size_t)B*CO*M1*M2;   // B*CO*CI*2*M1*M2 = 327680

    k_A1T<<<(N*IKP)/256, 256, 0, stream>>>(wp1r, wp1i, ty, A1T);
    k_E  <<<(IKP*N)/256, 256, 0, stream>>>(wp1r, wp1i, ty, E1);
    k_A2 <<<(IKQ*N)/256, 256, 0, stream>>>(wp2r, wp2i, tx, A2);
    k_E  <<<(IKQ*N)/256, 256, 0, stream>>>(wp2r, wp2i, tx, E2);
    k_W2N<<<(IKP*N)/256, 256, 0, stream>>>(wrr, wri, A2, W2N);

    // forward fft2: rows (real in) then cols
    k_fft_rows<0,1,0><<<(B*CI*N)/16, 256, 0, stream>>>((const void*)x, bufA);
    k_fft_cols<0,0,0><<<B*CI*8, 256, 0, stream>>>(bufA, alpha, nullptr);

    k_res1<<<N*8, 256, 0, stream>>>(alpha, A1T, W2N, res1);
    k_S_res2<<<B*CI*2, 512, 0, stream>>>(alpha, A2, A1T, part);
    k_res2_red<<<B*CO, 128, 0, stream>>>(part, wrr, wri, res2);

    // inverse fft2: rows (1/N) then cols (real out, 1/N)
    k_fft_rows<1,0,1><<<(B*CO*N)/16, 256, 0, stream>>>((const void*)res1, bufA);
    k_fft_cols<1,1,1><<<B*CO*8, 256, 0, stream>>>(bufA, nullptr, out);
    k_x2<<<B*CO*4, 256, 0, stream>>>(res2, E1, E2, out);
}